// Round 1
// baseline (26863.916 us; speedup 1.0000x reference)
//
#include <hip/hip_runtime.h>
#include <hip/hip_bf16.h>
#include <math.h>

#define L_   3
#define D_   256
#define H_   8
#define DFF_ 1024
#define DEP_ 40
#define B_   8
#define S_   512
#define DK_  32
#define NEG_ (-1e18f)

// ---------------------------------------------------------------------------
// Elementwise copy (src -> x), float4 vectorized
// ---------------------------------------------------------------------------
__global__ void copy_kernel(const float4* __restrict__ in, float4* __restrict__ out, int n4) {
    int i = blockIdx.x * blockDim.x + threadIdx.x;
    if (i < n4) out[i] = in[i];
}

// ---------------------------------------------------------------------------
// Tiled fp32 GEMM: C[m,n] = (A[m,:]@W[:,n] + bias[n]) * scale (+resid) (relu?)
// BM=BN=64, BK=16, 256 threads, 4x4 per thread. M,N,K all divisible by tile.
// ---------------------------------------------------------------------------
template<bool RELU>
__global__ __launch_bounds__(256)
void gemm_bias(const float* __restrict__ A, const float* __restrict__ W,
               const float* __restrict__ bias, const float* __restrict__ resid,
               float* __restrict__ C, int M, int N, int K, float scale)
{
    const int BM = 64, BN = 64, BK = 16;
    __shared__ float As[BK][BM + 1];
    __shared__ float Bs[BK][BN + 1];
    int bm = blockIdx.y * BM;
    int bn = blockIdx.x * BN;
    int tid = threadIdx.x;
    int tx = tid & 15, ty = tid >> 4;
    float acc[4][4] = {};
    for (int k0 = 0; k0 < K; k0 += BK) {
        #pragma unroll
        for (int i = 0; i < 4; ++i) {
            int idx = tid + i * 256;           // 0..1023 over 64x16 A tile
            int m = idx >> 4, kk = idx & 15;
            As[kk][m] = A[(size_t)(bm + m) * K + k0 + kk];
        }
        #pragma unroll
        for (int i = 0; i < 4; ++i) {
            int idx = tid + i * 256;           // 0..1023 over 16x64 B tile
            int kk = idx >> 6, n = idx & 63;
            Bs[kk][n] = W[(size_t)(k0 + kk) * N + bn + n];
        }
        __syncthreads();
        #pragma unroll
        for (int kk = 0; kk < BK; ++kk) {
            float a[4], bb[4];
            #pragma unroll
            for (int i = 0; i < 4; ++i) a[i] = As[kk][ty * 4 + i];
            #pragma unroll
            for (int j = 0; j < 4; ++j) bb[j] = Bs[kk][tx * 4 + j];
            #pragma unroll
            for (int i = 0; i < 4; ++i)
                #pragma unroll
                for (int j = 0; j < 4; ++j)
                    acc[i][j] += a[i] * bb[j];
        }
        __syncthreads();
    }
    #pragma unroll
    for (int i = 0; i < 4; ++i) {
        int m = bm + ty * 4 + i;
        #pragma unroll
        for (int j = 0; j < 4; ++j) {
            int n = bn + tx * 4 + j;
            float v = (acc[i][j] + bias[n]) * scale;
            if (resid) v += resid[(size_t)m * N + n];
            if (RELU) v = fmaxf(v, 0.f);
            C[(size_t)m * N + n] = v;
        }
    }
}

// ---------------------------------------------------------------------------
// Fused structure-aware attention. One block (256 thr) per (b, q) row.
//   scores[h,k] = q[h,:]·k[k,h,:] + q[h,:]·(structure[q,k,:]@Wsk + bsk)
//   masked -> softmax -> ctx[h,d] = sum_k p * (v[k,h,d] + sv[k,d])
// q is pre-scaled by 1/sqrt(DK). beta=1 folded into (v+sv).
// LDS: q(1K) + Wsk/Wsv(10K) + scores(16K) + sv(67.6K, pad 33) ≈ 93 KB.
// ---------------------------------------------------------------------------
__global__ __launch_bounds__(256, 1)
void attn_kernel(const float* __restrict__ qb,   // [B,S,D] scaled
                 const float* __restrict__ kb,   // [B,S,D]
                 const float* __restrict__ vb,   // [B,S,D]
                 const float* __restrict__ structure, // [B,S,S,DEP]
                 const int*   __restrict__ mask, // [B,S,S]
                 const int*   __restrict__ kpm,  // [B,S]
                 const float* __restrict__ Wsk, const float* __restrict__ bsk,
                 const float* __restrict__ Wsv, const float* __restrict__ bsv,
                 float* __restrict__ ctx)        // [B,S,D]
{
    __shared__ float q_s[D_];
    __shared__ float wsk_s[DEP_ * DK_];
    __shared__ float wsv_s[DEP_ * DK_];
    __shared__ float bsk_s[DK_], bsv_s[DK_];
    __shared__ float sc[H_ * S_];        // scores, then p=exp(s-m)
    __shared__ float sv_s[S_ * 33];      // [k][d] padded stride 33

    const int b   = blockIdx.x / S_;
    const int qi  = blockIdx.x % S_;
    const int tid = threadIdx.x;
    const int h      = tid >> 5;   // 0..7
    const int lane32 = tid & 31;   // d

    q_s[tid] = qb[((size_t)b * S_ + qi) * D_ + tid];
    for (int i = tid; i < DEP_ * DK_; i += 256) { wsk_s[i] = Wsk[i]; wsv_s[i] = Wsv[i]; }
    if (tid < DK_) { bsk_s[tid] = bsk[tid]; bsv_s[tid] = bsv[tid]; }
    __syncthreads();

    // Phase A: qk dot products. Per k: coalesced 1KB load, 32-lane reduce.
    const float* kbase = kb + (size_t)b * S_ * D_;
    #pragma unroll 4
    for (int k = 0; k < S_; ++k) {
        float p = q_s[tid] * kbase[(size_t)k * D_ + tid];
        #pragma unroll
        for (int off = 16; off; off >>= 1) p += __shfl_xor(p, off);
        if (lane32 == 0) sc[h * S_ + k] = p;
    }
    __syncthreads();

    // Phase B: structure projection + bias + mask. 2 keys per thread.
    for (int k = tid; k < S_; k += 256) {
        const float* st = structure + (((size_t)b * S_ + qi) * S_ + k) * DEP_;
        float stv[DEP_];
        #pragma unroll
        for (int j = 0; j < DEP_; ++j) stv[j] = st[j];
        float skv[DK_], svv[DK_];
        #pragma unroll
        for (int d = 0; d < DK_; ++d) { skv[d] = bsk_s[d]; svv[d] = bsv_s[d]; }
        #pragma unroll
        for (int j = 0; j < DEP_; ++j) {
            float s = stv[j];
            #pragma unroll
            for (int d = 0; d < DK_; ++d) {
                skv[d] += s * wsk_s[j * DK_ + d];
                svv[d] += s * wsv_s[j * DK_ + d];
            }
        }
        #pragma unroll
        for (int d = 0; d < DK_; ++d) sv_s[k * 33 + d] = svv[d];
        bool dead = (mask[((size_t)b * S_ + qi) * S_ + k] == 0) || (kpm[b * S_ + k] == 0);
        #pragma unroll
        for (int hh = 0; hh < H_; ++hh) {
            float bias = 0.f;
            #pragma unroll
            for (int d = 0; d < DK_; ++d) bias += q_s[hh * DK_ + d] * skv[d];
            float v = sc[hh * S_ + k] + bias;
            sc[hh * S_ + k] = dead ? NEG_ : v;
        }
    }
    __syncthreads();

    // Phase C: softmax per head (8 groups of 32 lanes).
    float mx = -INFINITY;
    for (int k = lane32; k < S_; k += 32) mx = fmaxf(mx, sc[h * S_ + k]);
    #pragma unroll
    for (int off = 16; off; off >>= 1) mx = fmaxf(mx, __shfl_xor(mx, off));
    float sum = 0.f;
    for (int k = lane32; k < S_; k += 32) {
        float e = expf(sc[h * S_ + k] - mx);
        sc[h * S_ + k] = e;
        sum += e;
    }
    #pragma unroll
    for (int off = 16; off; off >>= 1) sum += __shfl_xor(sum, off);
    float inv = 1.f / sum;
    __syncthreads();

    // Phase D: ctx[h,d] = inv * sum_k p[h,k] * (v[k,h,d] + sv[k,d])
    const float* vbase = vb + (size_t)b * S_ * D_ + tid;
    float acc = 0.f;
    #pragma unroll 4
    for (int k = 0; k < S_; ++k) {
        acc += sc[h * S_ + k] * (vbase[(size_t)k * D_] + sv_s[k * 33 + lane32]);
    }
    ctx[((size_t)b * S_ + qi) * D_ + tid] = acc * inv;
}

// ---------------------------------------------------------------------------
// LayerNorm over last dim (256). One block per row.
// ---------------------------------------------------------------------------
__global__ __launch_bounds__(256)
void ln_kernel(const float* __restrict__ x, const float* __restrict__ g,
               const float* __restrict__ b, float* __restrict__ out)
{
    int row = blockIdx.x, tid = threadIdx.x;
    float v = x[(size_t)row * D_ + tid];
    float s = v, ss = v * v;
    #pragma unroll
    for (int off = 32; off; off >>= 1) {
        s  += __shfl_xor(s, off);
        ss += __shfl_xor(ss, off);
    }
    __shared__ float rs[4], rss[4];
    int wid = tid >> 6, lane = tid & 63;
    if (lane == 0) { rs[wid] = s; rss[wid] = ss; }
    __syncthreads();
    float sum  = rs[0] + rs[1] + rs[2] + rs[3];
    float ssum = rss[0] + rss[1] + rss[2] + rss[3];
    float mean = sum * (1.f / D_);
    float var  = ssum * (1.f / D_) - mean * mean;
    out[(size_t)row * D_ + tid] = (v - mean) * rsqrtf(var + 1e-6f) * g[tid] + b[tid];
}

// ---------------------------------------------------------------------------
extern "C" void kernel_launch(void* const* d_in, const int* in_sizes, int n_in,
                              void* d_out, int out_size, void* d_ws, size_t ws_size,
                              hipStream_t stream)
{
    (void)in_sizes; (void)n_in; (void)out_size; (void)ws_size;
    const float* src       = (const float*)d_in[0];
    const int*   mask      = (const int*)  d_in[1];
    const int*   kpm       = (const int*)  d_in[2];
    const float* structure = (const float*)d_in[3];
    const float* Wq  = (const float*)d_in[4];  const float* bq  = (const float*)d_in[5];
    const float* Wk  = (const float*)d_in[6];  const float* bk  = (const float*)d_in[7];
    const float* Wv  = (const float*)d_in[8];  const float* bv  = (const float*)d_in[9];
    const float* Wo  = (const float*)d_in[10]; const float* bo  = (const float*)d_in[11];
    const float* Wsk = (const float*)d_in[12]; const float* bsk = (const float*)d_in[13];
    const float* Wsv = (const float*)d_in[14]; const float* bsv = (const float*)d_in[15];
    const float* ln1g = (const float*)d_in[16]; const float* ln1b = (const float*)d_in[17];
    const float* Wf1 = (const float*)d_in[18]; const float* bf1 = (const float*)d_in[19];
    const float* Wf2 = (const float*)d_in[20]; const float* bf2 = (const float*)d_in[21];
    const float* lnfg = (const float*)d_in[22]; const float* lnfb = (const float*)d_in[23];

    const int M = B_ * S_;                 // 4096
    const size_t NB = (size_t)M * D_;      // 1,048,576 floats per activation buffer
    float* ws   = (float*)d_ws;
    float* x    = ws;
    float* qb   = ws + 1 * NB;
    float* kb2  = ws + 2 * NB;
    float* vb2  = ws + 3 * NB;
    float* ctx  = ws + 4 * NB;
    float* outb = ws + 5 * NB;
    float* hln  = ws + 6 * NB;
    float* f1   = ws + 7 * NB;             // 4M floats (M x DFF)

    copy_kernel<<<1024, 256, 0, stream>>>((const float4*)src, (float4*)x, (int)(NB / 4));

    const float qscale = 0.17677669529663689f; // 1/sqrt(32)
    for (int i = 0; i < L_; ++i) {
        const float* Wq_i = Wq + (size_t)i * D_ * D_;
        const float* Wk_i = Wk + (size_t)i * D_ * D_;
        const float* Wv_i = Wv + (size_t)i * D_ * D_;
        const float* Wo_i = Wo + (size_t)i * D_ * D_;
        gemm_bias<false><<<dim3(D_ / 64, M / 64), 256, 0, stream>>>(
            x, Wq_i, bq + i * D_, nullptr, qb, M, D_, D_, qscale);
        gemm_bias<false><<<dim3(D_ / 64, M / 64), 256, 0, stream>>>(
            x, Wk_i, bk + i * D_, nullptr, kb2, M, D_, D_, 1.f);
        gemm_bias<false><<<dim3(D_ / 64, M / 64), 256, 0, stream>>>(
            x, Wv_i, bv + i * D_, nullptr, vb2, M, D_, D_, 1.f);
        attn_kernel<<<B_ * S_, 256, 0, stream>>>(
            qb, kb2, vb2, structure, mask, kpm,
            Wsk + (size_t)i * DEP_ * DK_, bsk + i * DK_,
            Wsv + (size_t)i * DEP_ * DK_, bsv + i * DK_, ctx);
        gemm_bias<false><<<dim3(D_ / 64, M / 64), 256, 0, stream>>>(
            ctx, Wo_i, bo + i * D_, x, outb, M, D_, D_, 1.f);
        ln_kernel<<<M, 256, 0, stream>>>(outb, ln1g + i * D_, ln1b + i * D_, hln);
        gemm_bias<true><<<dim3(DFF_ / 64, M / 64), 256, 0, stream>>>(
            hln, Wf1 + (size_t)i * D_ * DFF_, bf1 + i * DFF_, nullptr, f1, M, DFF_, D_, 1.f);
        gemm_bias<false><<<dim3(D_ / 64, M / 64), 256, 0, stream>>>(
            f1, Wf2 + (size_t)i * DFF_ * D_, bf2 + i * D_, outb, x, M, D_, DFF_, 1.f);
    }
    ln_kernel<<<M, 256, 0, stream>>>(x, lnfg, lnfb, (float*)d_out);
}

// Round 2
// 4982.692 us; speedup vs baseline: 5.3914x; 5.3914x over previous
//
#include <hip/hip_runtime.h>
#include <hip/hip_bf16.h>
#include <math.h>

#define L_   3
#define D_   256
#define H_   8
#define DFF_ 1024
#define DEP_ 40
#define B_   8
#define S_   512
#define DK_  32
#define NEG_ (-1e18f)

// ---------------------------------------------------------------------------
// Elementwise copy (src -> x), float4 vectorized
// ---------------------------------------------------------------------------
__global__ void copy_kernel(const float4* __restrict__ in, float4* __restrict__ out, int n4) {
    int i = blockIdx.x * blockDim.x + threadIdx.x;
    if (i < n4) out[i] = in[i];
}

// ---------------------------------------------------------------------------
// Tiled fp32 GEMM: C[m,n] = (A[m,:]@W[:,n] + bias[n]) * scale (+resid) (relu?)
// BM=BN=64, BK=16, 256 threads, 4x4 per thread. M,N,K all divisible by tile.
// ---------------------------------------------------------------------------
template<bool RELU>
__global__ __launch_bounds__(256)
void gemm_bias(const float* __restrict__ A, const float* __restrict__ W,
               const float* __restrict__ bias, const float* __restrict__ resid,
               float* __restrict__ C, int M, int N, int K, float scale)
{
    const int BM = 64, BN = 64, BK = 16;
    __shared__ float As[BK][BM + 1];
    __shared__ float Bs[BK][BN + 1];
    int bm = blockIdx.y * BM;
    int bn = blockIdx.x * BN;
    int tid = threadIdx.x;
    int tx = tid & 15, ty = tid >> 4;
    float acc[4][4] = {};
    for (int k0 = 0; k0 < K; k0 += BK) {
        #pragma unroll
        for (int i = 0; i < 4; ++i) {
            int idx = tid + i * 256;           // 0..1023 over 64x16 A tile
            int m = idx >> 4, kk = idx & 15;
            As[kk][m] = A[(size_t)(bm + m) * K + k0 + kk];
        }
        #pragma unroll
        for (int i = 0; i < 4; ++i) {
            int idx = tid + i * 256;           // 0..1023 over 16x64 B tile
            int kk = idx >> 6, n = idx & 63;
            Bs[kk][n] = W[(size_t)(k0 + kk) * N + bn + n];
        }
        __syncthreads();
        #pragma unroll
        for (int kk = 0; kk < BK; ++kk) {
            float a[4], bb[4];
            #pragma unroll
            for (int i = 0; i < 4; ++i) a[i] = As[kk][ty * 4 + i];
            #pragma unroll
            for (int j = 0; j < 4; ++j) bb[j] = Bs[kk][tx * 4 + j];
            #pragma unroll
            for (int i = 0; i < 4; ++i)
                #pragma unroll
                for (int j = 0; j < 4; ++j)
                    acc[i][j] += a[i] * bb[j];
        }
        __syncthreads();
    }
    #pragma unroll
    for (int i = 0; i < 4; ++i) {
        int m = bm + ty * 4 + i;
        #pragma unroll
        for (int j = 0; j < 4; ++j) {
            int n = bn + tx * 4 + j;
            float v = (acc[i][j] + bias[n]) * scale;
            if (resid) v += resid[(size_t)m * N + n];
            if (RELU) v = fmaxf(v, 0.f);
            C[(size_t)m * N + n] = v;
        }
    }
}

// ---------------------------------------------------------------------------
// Fused structure-aware attention, v2. One block (256 thr) per (b, q) row.
// Algebraic refactor to avoid materializing sk/sv per key:
//   bias[h,k] = q_h·(st[k]@Wsk + bsk) = st[k]·wqk[h] + hb[h],
//       where wqk[h,dep] = Sum_d Wsk[dep,d] q[h,d]  (computed once per block)
//   Sum_k p[h,k]·(st[k]@Wsv + bsv) = ps[h]@Wsv + bsv,
//       where ps[h,dep] = Sum_k p[h,k] st[k,dep]    (online accumulated)
// Online softmax over 8 tiles of 64 keys; st tile staged in LDS (stride 41
// pad -> 2-way bank aliasing only, which is free on gfx950).
// Thread layout: tid = h*32 + lane  (h = head, lane = dk / dep index).
// ---------------------------------------------------------------------------
#define TK_ 64
#define STP_ 41   // st_s row stride (pad 40 -> 41)

__global__ __launch_bounds__(256, 4)
void attn_kernel(const float* __restrict__ qb,   // [B,S,D] pre-scaled by 1/sqrt(dk)
                 const float* __restrict__ kb,   // [B,S,D]
                 const float* __restrict__ vb,   // [B,S,D]
                 const float* __restrict__ structure, // [B,S,S,DEP]
                 const int*   __restrict__ mask, // [B,S,S]
                 const int*   __restrict__ kpm,  // [B,S]
                 const float* __restrict__ Wsk, const float* __restrict__ bsk,
                 const float* __restrict__ Wsv, const float* __restrict__ bsv,
                 float* __restrict__ ctx)        // [B,S,D]
{
    __shared__ float q_s[D_];
    __shared__ float wqk_s[H_ * DEP_];
    __shared__ float hb_s[H_];
    __shared__ float st_s[TK_ * STP_];
    __shared__ float sc_s[H_ * TK_];
    __shared__ int   dead_s[TK_];
    __shared__ float ps_s[H_ * DEP_];

    const int b   = blockIdx.x / S_;
    const int qi  = blockIdx.x % S_;
    const int tid = threadIdx.x;
    const int h    = tid >> 5;
    const int lane = tid & 31;

    q_s[tid] = qb[((size_t)b * S_ + qi) * D_ + tid];
    __syncthreads();

    // wqk[h][dep] = Wsk[dep,:]·q[h,:] ; hb[h] = bsk·q[h,:]
    for (int p = tid; p < H_ * DEP_; p += 256) {
        int hh = p / DEP_, dep = p - hh * DEP_;
        const float* wr = Wsk + dep * DK_;
        const float* qr = q_s + hh * DK_;
        float s = 0.f;
        #pragma unroll
        for (int d = 0; d < DK_; ++d) s += qr[d] * wr[d];
        wqk_s[hh * DEP_ + dep] = s;
    }
    if (tid < H_) {
        float s = 0.f;
        #pragma unroll
        for (int d = 0; d < DK_; ++d) s += q_s[tid * DK_ + d] * bsk[d];
        hb_s[tid] = s;
    }

    const float* kbase = kb + (size_t)b * S_ * D_;
    const float* vbase = vb + (size_t)b * S_ * D_;
    const float* strow = structure + (size_t)(b * S_ + qi) * S_ * DEP_;
    const int*   mrow  = mask + (size_t)(b * S_ + qi) * S_;
    const int*   krow  = kpm + (size_t)b * S_;

    float m_run = -INFINITY, l_run = 0.f;
    float vacc = 0.f;           // ctx_v for (h, d=lane)
    float ps0 = 0.f, ps1 = 0.f; // ps[h][lane], ps[h][32+lane] (lane<8)

    for (int t = 0; t < S_ / TK_; ++t) {
        const int k0 = t * TK_;
        // stage st tile (64 x 40, contiguous in global) + dead flags
        for (int i = tid; i < TK_ * DEP_; i += 256) {
            int kk = i / DEP_, dep = i - kk * DEP_;
            st_s[kk * STP_ + dep] = strow[(size_t)k0 * DEP_ + i];
        }
        if (tid < TK_) dead_s[tid] = (mrow[k0 + tid] == 0) | (krow[k0 + tid] == 0);
        // phase A: qk scores for 64 keys (block-wide dot + 32-lane reduce)
        for (int kk = 0; kk < TK_; ++kk) {
            float p = q_s[tid] * kbase[(size_t)(k0 + kk) * D_ + tid];
            #pragma unroll
            for (int off = 16; off; off >>= 1) p += __shfl_xor(p, off);
            if (lane == 0) sc_s[h * TK_ + kk] = p;
        }
        __syncthreads();
        // phase B: structure bias + mask. 2 (h,kk) pairs per thread.
        #pragma unroll
        for (int rep = 0; rep < 2; ++rep) {
            int p = tid + rep * 256;
            int hh = p >> 6, kk = p & 63;
            const float* sr = st_s + kk * STP_;
            const float* wr = wqk_s + hh * DEP_;
            float bias = hb_s[hh];
            #pragma unroll
            for (int j = 0; j < DEP_; ++j) bias += sr[j] * wr[j];
            float v = sc_s[hh * TK_ + kk] + bias;
            sc_s[hh * TK_ + kk] = dead_s[kk] ? NEG_ : v;
        }
        __syncthreads();
        // phase C: online softmax update for this tile
        float s0 = sc_s[h * TK_ + lane];
        float s1 = sc_s[h * TK_ + 32 + lane];
        float tm = fmaxf(s0, s1);
        #pragma unroll
        for (int off = 16; off; off >>= 1) tm = fmaxf(tm, __shfl_xor(tm, off));
        float m_new = fmaxf(m_run, tm);
        float alpha = __expf(m_run - m_new);   // 0 on first tile (m_run=-inf)
        float e0 = __expf(s0 - m_new), e1 = __expf(s1 - m_new);
        sc_s[h * TK_ + lane] = e0;
        sc_s[h * TK_ + 32 + lane] = e1;
        float psum = e0 + e1;
        #pragma unroll
        for (int off = 16; off; off >>= 1) psum += __shfl_xor(psum, off);
        l_run = l_run * alpha + psum;
        m_run = m_new;
        vacc *= alpha; ps0 *= alpha; ps1 *= alpha;
        __syncthreads();
        // phase D: accumulate ctx_v and ps
        for (int kk = 0; kk < TK_; ++kk) {
            float e = sc_s[h * TK_ + kk];
            vacc += e * vbase[(size_t)(k0 + kk) * D_ + tid];
            ps0 += e * st_s[kk * STP_ + lane];
            if (lane < DEP_ - 32) ps1 += e * st_s[kk * STP_ + 32 + lane];
        }
        __syncthreads();
    }

    // epilogue: ctx = (vacc + ps@Wsv)/l + bsv
    ps_s[h * DEP_ + lane] = ps0;
    if (lane < DEP_ - 32) ps_s[h * DEP_ + 32 + lane] = ps1;
    __syncthreads();
    float psv = 0.f;
    #pragma unroll
    for (int j = 0; j < DEP_; ++j) psv += ps_s[h * DEP_ + j] * Wsv[j * DK_ + lane];
    ctx[((size_t)b * S_ + qi) * D_ + tid] = (vacc + psv) / l_run + bsv[lane];
}

// ---------------------------------------------------------------------------
// LayerNorm over last dim (256). One block per row.
// ---------------------------------------------------------------------------
__global__ __launch_bounds__(256)
void ln_kernel(const float* __restrict__ x, const float* __restrict__ g,
               const float* __restrict__ b, float* __restrict__ out)
{
    int row = blockIdx.x, tid = threadIdx.x;
    float v = x[(size_t)row * D_ + tid];
    float s = v, ss = v * v;
    #pragma unroll
    for (int off = 32; off; off >>= 1) {
        s  += __shfl_xor(s, off);
        ss += __shfl_xor(ss, off);
    }
    __shared__ float rs[4], rss[4];
    int wid = tid >> 6, lane = tid & 63;
    if (lane == 0) { rs[wid] = s; rss[wid] = ss; }
    __syncthreads();
    float sum  = rs[0] + rs[1] + rs[2] + rs[3];
    float ssum = rss[0] + rss[1] + rss[2] + rss[3];
    float mean = sum * (1.f / D_);
    float var  = ssum * (1.f / D_) - mean * mean;
    out[(size_t)row * D_ + tid] = (v - mean) * rsqrtf(var + 1e-6f) * g[tid] + b[tid];
}

// ---------------------------------------------------------------------------
extern "C" void kernel_launch(void* const* d_in, const int* in_sizes, int n_in,
                              void* d_out, int out_size, void* d_ws, size_t ws_size,
                              hipStream_t stream)
{
    (void)in_sizes; (void)n_in; (void)out_size; (void)ws_size;
    const float* src       = (const float*)d_in[0];
    const int*   mask      = (const int*)  d_in[1];
    const int*   kpm       = (const int*)  d_in[2];
    const float* structure = (const float*)d_in[3];
    const float* Wq  = (const float*)d_in[4];  const float* bq  = (const float*)d_in[5];
    const float* Wk  = (const float*)d_in[6];  const float* bk  = (const float*)d_in[7];
    const float* Wv  = (const float*)d_in[8];  const float* bv  = (const float*)d_in[9];
    const float* Wo  = (const float*)d_in[10]; const float* bo  = (const float*)d_in[11];
    const float* Wsk = (const float*)d_in[12]; const float* bsk = (const float*)d_in[13];
    const float* Wsv = (const float*)d_in[14]; const float* bsv = (const float*)d_in[15];
    const float* ln1g = (const float*)d_in[16]; const float* ln1b = (const float*)d_in[17];
    const float* Wf1 = (const float*)d_in[18]; const float* bf1 = (const float*)d_in[19];
    const float* Wf2 = (const float*)d_in[20]; const float* bf2 = (const float*)d_in[21];
    const float* lnfg = (const float*)d_in[22]; const float* lnfb = (const float*)d_in[23];

    const int M = B_ * S_;                 // 4096
    const size_t NB = (size_t)M * D_;      // 1,048,576 floats per activation buffer
    float* ws   = (float*)d_ws;
    float* x    = ws;
    float* qb   = ws + 1 * NB;
    float* kb2  = ws + 2 * NB;
    float* vb2  = ws + 3 * NB;
    float* ctx  = ws + 4 * NB;
    float* outb = ws + 5 * NB;
    float* hln  = ws + 6 * NB;
    float* f1   = ws + 7 * NB;             // 4M floats (M x DFF)

    copy_kernel<<<1024, 256, 0, stream>>>((const float4*)src, (float4*)x, (int)(NB / 4));

    const float qscale = 0.17677669529663689f; // 1/sqrt(32)
    for (int i = 0; i < L_; ++i) {
        const float* Wq_i = Wq + (size_t)i * D_ * D_;
        const float* Wk_i = Wk + (size_t)i * D_ * D_;
        const float* Wv_i = Wv + (size_t)i * D_ * D_;
        const float* Wo_i = Wo + (size_t)i * D_ * D_;
        gemm_bias<false><<<dim3(D_ / 64, M / 64), 256, 0, stream>>>(
            x, Wq_i, bq + i * D_, nullptr, qb, M, D_, D_, qscale);
        gemm_bias<false><<<dim3(D_ / 64, M / 64), 256, 0, stream>>>(
            x, Wk_i, bk + i * D_, nullptr, kb2, M, D_, D_, 1.f);
        gemm_bias<false><<<dim3(D_ / 64, M / 64), 256, 0, stream>>>(
            x, Wv_i, bv + i * D_, nullptr, vb2, M, D_, D_, 1.f);
        attn_kernel<<<B_ * S_, 256, 0, stream>>>(
            qb, kb2, vb2, structure, mask, kpm,
            Wsk + (size_t)i * DEP_ * DK_, bsk + i * DK_,
            Wsv + (size_t)i * DEP_ * DK_, bsv + i * DK_, ctx);
        gemm_bias<false><<<dim3(D_ / 64, M / 64), 256, 0, stream>>>(
            ctx, Wo_i, bo + i * D_, x, outb, M, D_, D_, 1.f);
        ln_kernel<<<M, 256, 0, stream>>>(outb, ln1g + i * D_, ln1b + i * D_, hln);
        gemm_bias<true><<<dim3(DFF_ / 64, M / 64), 256, 0, stream>>>(
            hln, Wf1 + (size_t)i * D_ * DFF_, bf1 + i * DFF_, nullptr, f1, M, DFF_, D_, 1.f);
        gemm_bias<false><<<dim3(D_ / 64, M / 64), 256, 0, stream>>>(
            f1, Wf2 + (size_t)i * DFF_ * D_, bf2 + i * D_, outb, x, M, D_, DFF_, 1.f);
    }
    ln_kernel<<<M, 256, 0, stream>>>(x, lnfg, lnfb, (float*)d_out);
}

// Round 3
// 2672.755 us; speedup vs baseline: 10.0510x; 1.8643x over previous
//
#include <hip/hip_runtime.h>
#include <hip/hip_bf16.h>
#include <math.h>

#define L_   3
#define D_   256
#define H_   8
#define DFF_ 1024
#define DEP_ 40
#define B_   8
#define S_   512
#define DK_  32
#define NEG_ (-1e18f)
#define TK3  32   // attn key-tile

// ---------------------------------------------------------------------------
// Elementwise copy (src -> x), float4 vectorized
// ---------------------------------------------------------------------------
__global__ void copy_kernel(const float4* __restrict__ in, float4* __restrict__ out, int n4) {
    int i = blockIdx.x * blockDim.x + threadIdx.x;
    if (i < n4) out[i] = in[i];
}

__device__ __forceinline__ float dot4(float4 a, float4 b) {
    return a.x * b.x + a.y * b.y + a.z * b.z + a.w * b.w;
}

// ---------------------------------------------------------------------------
// fp32 GEMM v2: BM=BN=64, BK=32, 4x4/thread, float4 LDS reads (2 b128 per
// 16 FMA -> VALU-bound, not LDS-bound). Fused bias/scale/resid/relu.
// ---------------------------------------------------------------------------
template<bool RELU>
__global__ __launch_bounds__(256)
void gemm_bias(const float* __restrict__ A, const float* __restrict__ W,
               const float* __restrict__ bias, const float* __restrict__ resid,
               float* __restrict__ C, int M, int N, int K, float scale)
{
    const int BK = 32;
    __shared__ float As[BK][68];   // [kk][m]
    __shared__ float Bs[BK][68];   // [kk][n]
    int bm = blockIdx.y * 64;
    int bn = blockIdx.x * 64;
    int tid = threadIdx.x;
    int tx = tid & 15, ty = tid >> 4;
    float acc[4][4] = {};
    for (int k0 = 0; k0 < K; k0 += BK) {
        #pragma unroll
        for (int r = 0; r < 2; ++r) {
            int c = tid + r * 256;
            int row = c >> 3, kc = c & 7;             // 64 rows x 8 f4-chunks
            float4 a = *(const float4*)&A[(size_t)(bm + row) * K + k0 + kc * 4];
            As[kc * 4 + 0][row] = a.x; As[kc * 4 + 1][row] = a.y;
            As[kc * 4 + 2][row] = a.z; As[kc * 4 + 3][row] = a.w;
        }
        #pragma unroll
        for (int r = 0; r < 2; ++r) {
            int c = tid + r * 256;
            int kk = c >> 4, n4 = c & 15;             // 32 k x 16 f4-chunks
            *(float4*)&Bs[kk][n4 * 4] =
                *(const float4*)&W[(size_t)(k0 + kk) * N + bn + n4 * 4];
        }
        __syncthreads();
        #pragma unroll
        for (int kk = 0; kk < BK; ++kk) {
            float4 av = *(float4*)&As[kk][ty * 4];
            float4 bv = *(float4*)&Bs[kk][tx * 4];
            float a[4] = {av.x, av.y, av.z, av.w};
            float bb[4] = {bv.x, bv.y, bv.z, bv.w};
            #pragma unroll
            for (int i = 0; i < 4; ++i)
                #pragma unroll
                for (int j = 0; j < 4; ++j)
                    acc[i][j] += a[i] * bb[j];
        }
        __syncthreads();
    }
    float4 bv = *(const float4*)&bias[bn + tx * 4];
    #pragma unroll
    for (int i = 0; i < 4; ++i) {
        int m = bm + ty * 4 + i;
        float4 v;
        v.x = (acc[i][0] + bv.x) * scale;
        v.y = (acc[i][1] + bv.y) * scale;
        v.z = (acc[i][2] + bv.z) * scale;
        v.w = (acc[i][3] + bv.w) * scale;
        if (resid) {
            float4 rv = *(const float4*)&resid[(size_t)m * N + bn + tx * 4];
            v.x += rv.x; v.y += rv.y; v.z += rv.z; v.w += rv.w;
        }
        if (RELU) {
            v.x = fmaxf(v.x, 0.f); v.y = fmaxf(v.y, 0.f);
            v.z = fmaxf(v.z, 0.f); v.w = fmaxf(v.w, 0.f);
        }
        *(float4*)&C[(size_t)m * N + bn + tx * 4] = v;
    }
}

// ---------------------------------------------------------------------------
// Fused structure-aware attention v3. One block (256 thr) per (b, q) row.
// Same algebra as v2 (wqk / ps refactor) but:
//  - wqk[40] and ps[40] in REGISTERS (float4) per thread (thread = h,lane)
//  - one key per thread per 32-key tile: softmax reduce once per tile
//  - st tile double-buffered in LDS, float4 staged; bias/ps read b128
//  - phase D (h,dk-layout) reads sc_s broadcast, v coalesced from global
// ---------------------------------------------------------------------------
__global__ __launch_bounds__(256)
void attn_kernel(const float* __restrict__ qb,   // [B,S,D] pre-scaled 1/sqrt(dk)
                 const float* __restrict__ kb,
                 const float* __restrict__ vb,
                 const float* __restrict__ structure, // [B,S,S,DEP]
                 const int*   __restrict__ mask,      // [B,S,S]
                 const int*   __restrict__ kpm,       // [B,S]
                 const float* __restrict__ Wsk, const float* __restrict__ bsk,
                 const float* __restrict__ Wsv, const float* __restrict__ bsv,
                 float* __restrict__ ctx)
{
    __shared__ float q_s[D_];
    __shared__ float wqk_s[H_][44];
    __shared__ float hb_s[H_];
    __shared__ float st_s[2][TK3][44];   // rows 16B-aligned (44*4=176)
    __shared__ float dead_s[2][TK3];     // additive 0 / -1e18
    __shared__ float sc_s[H_][TK3];

    const int b   = blockIdx.x / S_;
    const int qi  = blockIdx.x % S_;
    const int tid = threadIdx.x;
    const int h    = tid >> 5;
    const int lane = tid & 31;

    q_s[tid] = qb[((size_t)b * S_ + qi) * D_ + tid];
    __syncthreads();

    // wqk[h][dep] = q[h,:]·Wsk[dep,:]   (320 outputs, cooperative)
    for (int p = tid; p < H_ * DEP_; p += 256) {
        int hh = p / DEP_, dep = p - hh * DEP_;
        const float4* wr = (const float4*)(Wsk + dep * DK_);
        const float4* qr = (const float4*)(q_s + hh * DK_);
        float s = 0.f;
        #pragma unroll
        for (int c = 0; c < 8; ++c) s += dot4(qr[c], wr[c]);
        wqk_s[hh][dep] = s;
    }
    if (tid < H_) {
        const float4* qr = (const float4*)(q_s + tid * DK_);
        const float4* br = (const float4*)bsk;
        float s = 0.f;
        #pragma unroll
        for (int c = 0; c < 8; ++c) s += dot4(qr[c], br[c]);
        hb_s[tid] = s;
    }
    __syncthreads();

    float4 wqk_r[10];
    #pragma unroll
    for (int c = 0; c < 10; ++c) wqk_r[c] = *(float4*)&wqk_s[h][c * 4];
    const float hb = hb_s[h];

    const float* kbase = kb + (size_t)b * S_ * D_;
    const float* vbase = vb + (size_t)b * S_ * D_ + tid;
    const float* strow = structure + (size_t)(b * S_ + qi) * S_ * DEP_;
    const int*   mrow  = mask + (size_t)(b * S_ + qi) * S_;
    const int*   krow  = kpm + (size_t)b * S_;

    // pre-stage tile 0
    for (int c = tid; c < TK3 * 10; c += 256) {
        int kk = c / 10, d4 = c - kk * 10;
        *(float4*)&st_s[0][kk][d4 * 4] =
            *(const float4*)&strow[(size_t)kk * DEP_ + d4 * 4];
    }
    if (tid < TK3) dead_s[0][tid] = (mrow[tid] == 0 || krow[tid] == 0) ? NEG_ : 0.f;

    float m_run = -INFINITY, l_run = 0.f, vacc = 0.f;
    float4 ps_r[10];
    #pragma unroll
    for (int c = 0; c < 10; ++c) ps_r[c] = make_float4(0.f, 0.f, 0.f, 0.f);

    const float4* qp = (const float4*)(q_s + h * DK_);

    for (int t = 0; t < S_ / TK3; ++t) {
        const int buf = t & 1;
        const int k0  = t * TK3;
        __syncthreads();                    // staged buf ready; buf^1 free
        // stage tile t+1 into buf^1
        if (t + 1 < S_ / TK3) {
            const int kn = k0 + TK3;
            for (int c = tid; c < TK3 * 10; c += 256) {
                int kk = c / 10, d4 = c - kk * 10;
                *(float4*)&st_s[buf ^ 1][kk][d4 * 4] =
                    *(const float4*)&strow[(size_t)(kn + kk) * DEP_ + d4 * 4];
            }
            if (tid < TK3)
                dead_s[buf ^ 1][tid] = (mrow[kn + tid] == 0 || krow[kn + tid] == 0) ? NEG_ : 0.f;
        }
        // qk for this thread's key
        const int key = k0 + lane;
        const float4* kp = (const float4*)(kbase + (size_t)key * D_ + h * DK_);
        float kq = 0.f;
        #pragma unroll
        for (int c = 0; c < 8; ++c) kq += dot4(qp[c], kp[c]);
        // structure bias
        const float4* sp = (const float4*)&st_s[buf][lane][0];
        float bias = hb;
        #pragma unroll
        for (int c = 0; c < 10; ++c) bias += dot4(sp[c], wqk_r[c]);
        float sc = kq + bias + dead_s[buf][lane];
        // online softmax (one reduce per tile)
        float tm = sc;
        #pragma unroll
        for (int off = 16; off; off >>= 1) tm = fmaxf(tm, __shfl_xor(tm, off));
        float m_new = fmaxf(m_run, tm);
        float alpha = __expf(m_run - m_new);
        float e = __expf(sc - m_new);
        float psum = e;
        #pragma unroll
        for (int off = 16; off; off >>= 1) psum += __shfl_xor(psum, off);
        l_run = l_run * alpha + psum;
        m_run = m_new;
        sc_s[h][lane] = e;
        vacc *= alpha;
        #pragma unroll
        for (int c = 0; c < 10; ++c) {
            float4 sv = sp[c];
            ps_r[c].x = ps_r[c].x * alpha + e * sv.x;
            ps_r[c].y = ps_r[c].y * alpha + e * sv.y;
            ps_r[c].z = ps_r[c].z * alpha + e * sv.z;
            ps_r[c].w = ps_r[c].w * alpha + e * sv.w;
        }
        // phase D: ctx_v accumulate (thread as (h, dk=lane)); same-wave sc_s
        #pragma unroll 8
        for (int k = 0; k < TK3; ++k) {
            vacc += sc_s[h][k] * vbase[(size_t)(k0 + k) * D_];
        }
    }

    // reduce ps across the 32 lanes of this head
    float* pf = (float*)ps_r;
    #pragma unroll
    for (int j = 0; j < DEP_; ++j) {
        float v = pf[j];
        #pragma unroll
        for (int off = 16; off; off >>= 1) v += __shfl_xor(v, off);
        pf[j] = v;
    }
    float sv = 0.f;
    #pragma unroll
    for (int j = 0; j < DEP_; ++j) sv += pf[j] * Wsv[j * DK_ + lane];
    float invl = 1.f / l_run;
    ctx[((size_t)b * S_ + qi) * D_ + tid] = (vacc + sv) * invl + bsv[lane];
}

// ---------------------------------------------------------------------------
// LayerNorm over last dim (256). One block per row.
// ---------------------------------------------------------------------------
__global__ __launch_bounds__(256)
void ln_kernel(const float* __restrict__ x, const float* __restrict__ g,
               const float* __restrict__ b, float* __restrict__ out)
{
    int row = blockIdx.x, tid = threadIdx.x;
    float v = x[(size_t)row * D_ + tid];
    float s = v, ss = v * v;
    #pragma unroll
    for (int off = 32; off; off >>= 1) {
        s  += __shfl_xor(s, off);
        ss += __shfl_xor(ss, off);
    }
    __shared__ float rs[4], rss[4];
    int wid = tid >> 6, lane = tid & 63;
    if (lane == 0) { rs[wid] = s; rss[wid] = ss; }
    __syncthreads();
    float sum  = rs[0] + rs[1] + rs[2] + rs[3];
    float ssum = rss[0] + rss[1] + rss[2] + rss[3];
    float mean = sum * (1.f / D_);
    float var  = ssum * (1.f / D_) - mean * mean;
    out[(size_t)row * D_ + tid] = (v - mean) * rsqrtf(var + 1e-6f) * g[tid] + b[tid];
}

// ---------------------------------------------------------------------------
extern "C" void kernel_launch(void* const* d_in, const int* in_sizes, int n_in,
                              void* d_out, int out_size, void* d_ws, size_t ws_size,
                              hipStream_t stream)
{
    (void)in_sizes; (void)n_in; (void)out_size; (void)ws_size;
    const float* src       = (const float*)d_in[0];
    const int*   mask      = (const int*)  d_in[1];
    const int*   kpm       = (const int*)  d_in[2];
    const float* structure = (const float*)d_in[3];
    const float* Wq  = (const float*)d_in[4];  const float* bq  = (const float*)d_in[5];
    const float* Wk  = (const float*)d_in[6];  const float* bk  = (const float*)d_in[7];
    const float* Wv  = (const float*)d_in[8];  const float* bv  = (const float*)d_in[9];
    const float* Wo  = (const float*)d_in[10]; const float* bo  = (const float*)d_in[11];
    const float* Wsk = (const float*)d_in[12]; const float* bsk = (const float*)d_in[13];
    const float* Wsv = (const float*)d_in[14]; const float* bsv = (const float*)d_in[15];
    const float* ln1g = (const float*)d_in[16]; const float* ln1b = (const float*)d_in[17];
    const float* Wf1 = (const float*)d_in[18]; const float* bf1 = (const float*)d_in[19];
    const float* Wf2 = (const float*)d_in[20]; const float* bf2 = (const float*)d_in[21];
    const float* lnfg = (const float*)d_in[22]; const float* lnfb = (const float*)d_in[23];

    const int M = B_ * S_;                 // 4096
    const size_t NB = (size_t)M * D_;
    float* ws   = (float*)d_ws;
    float* x    = ws;
    float* qb   = ws + 1 * NB;
    float* kb2  = ws + 2 * NB;
    float* vb2  = ws + 3 * NB;
    float* ctx  = ws + 4 * NB;
    float* outb = ws + 5 * NB;
    float* hln  = ws + 6 * NB;
    float* f1   = ws + 7 * NB;             // M x DFF

    copy_kernel<<<1024, 256, 0, stream>>>((const float4*)src, (float4*)x, (int)(NB / 4));

    const float qscale = 0.17677669529663689f; // 1/sqrt(32)
    for (int i = 0; i < L_; ++i) {
        const float* Wq_i = Wq + (size_t)i * D_ * D_;
        const float* Wk_i = Wk + (size_t)i * D_ * D_;
        const float* Wv_i = Wv + (size_t)i * D_ * D_;
        const float* Wo_i = Wo + (size_t)i * D_ * D_;
        gemm_bias<false><<<dim3(D_ / 64, M / 64), 256, 0, stream>>>(
            x, Wq_i, bq + i * D_, nullptr, qb, M, D_, D_, qscale);
        gemm_bias<false><<<dim3(D_ / 64, M / 64), 256, 0, stream>>>(
            x, Wk_i, bk + i * D_, nullptr, kb2, M, D_, D_, 1.f);
        gemm_bias<false><<<dim3(D_ / 64, M / 64), 256, 0, stream>>>(
            x, Wv_i, bv + i * D_, nullptr, vb2, M, D_, D_, 1.f);
        attn_kernel<<<B_ * S_, 256, 0, stream>>>(
            qb, kb2, vb2, structure, mask, kpm,
            Wsk + (size_t)i * DEP_ * DK_, bsk + i * DK_,
            Wsv + (size_t)i * DEP_ * DK_, bsv + i * DK_, ctx);
        gemm_bias<false><<<dim3(D_ / 64, M / 64), 256, 0, stream>>>(
            ctx, Wo_i, bo + i * D_, x, outb, M, D_, D_, 1.f);
        ln_kernel<<<M, 256, 0, stream>>>(outb, ln1g + i * D_, ln1b + i * D_, hln);
        gemm_bias<true><<<dim3(DFF_ / 64, M / 64), 256, 0, stream>>>(
            hln, Wf1 + (size_t)i * D_ * DFF_, bf1 + i * DFF_, nullptr, f1, M, DFF_, D_, 1.f);
        gemm_bias<false><<<dim3(D_ / 64, M / 64), 256, 0, stream>>>(
            f1, Wf2 + (size_t)i * DFF_ * D_, bf2 + i * D_, outb, x, M, D_, DFF_, 1.f);
    }
    ln_kernel<<<M, 256, 0, stream>>>(x, lnfg, lnfb, (float*)d_out);
}